// Round 8
// baseline (589.628 us; speedup 1.0000x reference)
//
#include <hip/hip_runtime.h>

#define N_NODES  100000
#define N_EDGES  1600000
#define N_GRAPHS 1024
#define D        128
#define BN_EPS   1e-5f

// --- atomic-free CSR build geometry ---
#define FNSLICE      98                  // ceil(100000/1024) node slices
#define FSLICE_NODES 1024                // nodes per slice (d>>10)
#define FSLICE_CAP   20480               // queue cap: mean 16384, sigma~127
#define QCAP         96                  // per-block LDS bin: mean 41, +12 sigma
#define CCHUNK       4000
#define CGRID        400                 // 400*4000 == N_EDGES

typedef short bf16x8 __attribute__((ext_vector_type(8)));
typedef float f32x4  __attribute__((ext_vector_type(4)));

__device__ __forceinline__ ushort f2bf(float f) {        // RNE fp32->bf16
    unsigned int b = __float_as_uint(f);
    return (ushort)((b + 0x7fffu + ((b >> 16) & 1u)) >> 16);
}
__device__ __forceinline__ float bflo(unsigned int u) { return __uint_as_float(u << 16); }
__device__ __forceinline__ float bfhi(unsigned int u) { return __uint_as_float(u & 0xffff0000u); }
__device__ __forceinline__ unsigned int packbf(float x, float y) {
    return (unsigned int)f2bf(x) | ((unsigned int)f2bf(y) << 16);
}

// ---------------- CSR build (no global atomics on hot paths) ----------------

__global__ void zero_kernel(int* __restrict__ p, int n) {
    int i = blockIdx.x * blockDim.x + threadIdx.x;
    if (i < n) p[i] = 0;
}

__global__ __launch_bounds__(256) void compact_kernel(const int* __restrict__ src,
                                                      const int* __restrict__ dst,
                                                      unsigned int* __restrict__ squeue,
                                                      int* __restrict__ slice_tail) {
    __shared__ unsigned int qbuf[FNSLICE * QCAP];   // 37.6 KB
    __shared__ int qcnt[FNSLICE];
    __shared__ int qbase[FNSLICE];
    int t = threadIdx.x;
    for (int i = t; i < FNSLICE; i += 256) qcnt[i] = 0;
    __syncthreads();
    int e0 = blockIdx.x * CCHUNK;
    int eend = e0 + CCHUNK; if (eend > N_EDGES) eend = N_EDGES;
    for (int e = e0 + t; e < eend; e += 256) {
        int d = dst[e], s = src[e];
        int sl = d >> 10;
        unsigned int pk = ((unsigned int)(d & 1023) << 17) | (unsigned int)s;
        int pos = atomicAdd(&qcnt[sl], 1);
        if (pos < QCAP) qbuf[sl * QCAP + pos] = pk;
        else {  // ~never (12-sigma): direct spill, still correct
            int gp = atomicAdd(&slice_tail[sl], 1);
            squeue[(size_t)sl * FSLICE_CAP + gp] = pk;
        }
    }
    __syncthreads();
    for (int i = t; i < FNSLICE; i += 256) {
        int n = qcnt[i]; if (n > QCAP) n = QCAP;
        qbase[i] = atomicAdd(&slice_tail[i], n);
    }
    __syncthreads();
    // copy-out parallel across the 4 waves (was a serial 98-slice loop)
    int wv = t >> 6, ln = t & 63;
    for (int sl = wv; sl < FNSLICE; sl += 4) {
        int n = qcnt[sl]; if (n > QCAP) n = QCAP;
        int gb = qbase[sl];
        for (int i = ln; i < n; i += 64)
            squeue[(size_t)sl * FSLICE_CAP + gb + i] = qbuf[sl * QCAP + i];
    }
}

__global__ __launch_bounds__(128) void slice_scan(const int* __restrict__ slice_tail,
                                                  int* __restrict__ slice_base,
                                                  int* __restrict__ offsets) {
    __shared__ int part[128];
    int t = threadIdx.x;
    int v = (t < FNSLICE) ? slice_tail[t] : 0;
    part[t] = v;
    __syncthreads();
    for (int off = 1; off < 128; off <<= 1) {
        int u = (t >= off) ? part[t - off] : 0;
        __syncthreads();
        part[t] += u;
        __syncthreads();
    }
    if (t < FNSLICE) slice_base[t] = part[t] - v;
    if (t == 0) offsets[N_NODES] = N_EDGES;
}

__global__ __launch_bounds__(1024) void fill_local(const unsigned int* __restrict__ squeue,
                                                   const int* __restrict__ slice_tail,
                                                   const int* __restrict__ slice_base,
                                                   int* __restrict__ offsets,
                                                   int* __restrict__ csr_src) {
    __shared__ int hist[FSLICE_NODES];
    __shared__ int cur[FSLICE_NODES];
    int sl = blockIdx.x, t = threadIdx.x;
    int n = slice_tail[sl];
    size_t qb = (size_t)sl * FSLICE_CAP;
    int gbase = slice_base[sl];
    hist[t] = 0;
    __syncthreads();
    for (int i = t; i < n; i += 1024)
        atomicAdd(&hist[squeue[qb + i] >> 17], 1);
    __syncthreads();
    int v = hist[t];
    for (int off = 1; off < 1024; off <<= 1) {       // inclusive Hillis-Steele
        int u = (t >= off) ? hist[t - off] : 0;
        __syncthreads();
        hist[t] += u;
        __syncthreads();
    }
    int excl = hist[t] - v;
    cur[t] = excl;
    int node = sl * FSLICE_NODES + t;
    if (node < N_NODES) offsets[node] = gbase + excl;
    __syncthreads();
    for (int i = t; i < n; i += 1024) {
        unsigned int p = squeue[qb + i];
        int slot = atomicAdd(&cur[p >> 17], 1);      // LDS atomic
        csr_src[gbase + slot] = (int)(p & 0x1FFFFu);
    }
}

__global__ void gstart_kernel(const int* __restrict__ batch, int* __restrict__ gstart) {
    int g = blockIdx.x * blockDim.x + threadIdx.x;
    if (g > N_GRAPHS) return;
    int lo = 0, hi = N_NODES;
    while (lo < hi) {
        int mid = (lo + hi) >> 1;
        if (batch[mid] < g) lo = mid + 1; else hi = mid;
    }
    gstart[g] = lo;
}

// ---------------- precompute ----------------

__global__ __launch_bounds__(256) void cvt_x_kernel(const float* __restrict__ x,
                                                    ushort* __restrict__ xb) {
    size_t i = ((size_t)blockIdx.x * 256 + threadIdx.x) * 8;   // 6250 blocks exact
    float4 v0 = *(const float4*)(x + i);
    float4 v1 = *(const float4*)(x + i + 4);
    uint4 o;
    o.x = packbf(v0.x, v0.y); o.y = packbf(v0.z, v0.w);
    o.z = packbf(v1.x, v1.y); o.w = packbf(v1.z, v1.w);
    *(uint4*)(xb + i) = o;
}

__global__ __launch_bounds__(128) void prep_w_kernel(const float* __restrict__ W1,
                                                     const float* __restrict__ W2,
                                                     ushort* __restrict__ Wt) {
    int i = blockIdx.y, k = blockIdx.x, n = threadIdx.x, l = i >> 1;
    const float* W = (i & 1) ? (W2 + (size_t)l * D * D) : (W1 + (size_t)l * D * D);
    Wt[(size_t)i * D * D + n * D + k] = f2bf(W[k * D + n]);
}

__global__ __launch_bounds__(128) void prep_fold_kernel(
        const float* __restrict__ b1, const float* __restrict__ gamma,
        const float* __restrict__ beta, const float* __restrict__ mean,
        const float* __restrict__ var, const float* __restrict__ b2,
        float* __restrict__ folds) {
    int i = blockIdx.x, j = threadIdx.x, l = i >> 1;
    float s, o;
    if ((i & 1) == 0) {
        float sv = gamma[l * D + j] * rsqrtf(var[l * D + j] + BN_EPS);
        s = sv;
        o = (b1[l * D + j] - mean[l * D + j]) * sv + beta[l * D + j];
    } else {
        s = 1.0f;
        o = b2[l * D + j];
    }
    folds[(size_t)i * 2 * D + j]     = s;
    folds[(size_t)i * 2 * D + D + j] = o;
}

// ---------------- aggregation (bf16 rows, fp32 accumulate, 16 outstanding) ----------------
__global__ __launch_bounds__(256) void gather_bf16(const ushort* __restrict__ xb,
                                                   const int* __restrict__ offsets,
                                                   const int* __restrict__ csr_src,
                                                   ushort* __restrict__ hb) {
    int wv = threadIdx.x >> 6, lane = threadIdx.x & 63;
    int node = blockIdx.x * 4 + wv;           // 25000*4 == N_NODES
    const unsigned int* base = (const unsigned int*)xb;
    unsigned int u = base[(size_t)node * 64 + lane];
    float ax = bflo(u), ay = bfhi(u);
    int b = offsets[node], e = offsets[node + 1];
    int i = b;
    for (; i + 15 < e; i += 16) {             // 16 outstanding row loads
        int s0 = csr_src[i],      s1 = csr_src[i + 1],  s2 = csr_src[i + 2],  s3 = csr_src[i + 3];
        int s4 = csr_src[i + 4],  s5 = csr_src[i + 5],  s6 = csr_src[i + 6],  s7 = csr_src[i + 7];
        int s8 = csr_src[i + 8],  s9 = csr_src[i + 9],  sa = csr_src[i + 10], sb = csr_src[i + 11];
        int sc = csr_src[i + 12], sd = csr_src[i + 13], se = csr_src[i + 14], sf = csr_src[i + 15];
        unsigned int v0 = base[(size_t)s0 * 64 + lane];
        unsigned int v1 = base[(size_t)s1 * 64 + lane];
        unsigned int v2 = base[(size_t)s2 * 64 + lane];
        unsigned int v3 = base[(size_t)s3 * 64 + lane];
        unsigned int v4 = base[(size_t)s4 * 64 + lane];
        unsigned int v5 = base[(size_t)s5 * 64 + lane];
        unsigned int v6 = base[(size_t)s6 * 64 + lane];
        unsigned int v7 = base[(size_t)s7 * 64 + lane];
        unsigned int v8 = base[(size_t)s8 * 64 + lane];
        unsigned int v9 = base[(size_t)s9 * 64 + lane];
        unsigned int va = base[(size_t)sa * 64 + lane];
        unsigned int vb = base[(size_t)sb * 64 + lane];
        unsigned int vc = base[(size_t)sc * 64 + lane];
        unsigned int vd = base[(size_t)sd * 64 + lane];
        unsigned int ve = base[(size_t)se * 64 + lane];
        unsigned int vf = base[(size_t)sf * 64 + lane];
        ax += bflo(v0) + bflo(v1) + bflo(v2) + bflo(v3)
            + bflo(v4) + bflo(v5) + bflo(v6) + bflo(v7)
            + bflo(v8) + bflo(v9) + bflo(va) + bflo(vb)
            + bflo(vc) + bflo(vd) + bflo(ve) + bflo(vf);
        ay += bfhi(v0) + bfhi(v1) + bfhi(v2) + bfhi(v3)
            + bfhi(v4) + bfhi(v5) + bfhi(v6) + bfhi(v7)
            + bfhi(v8) + bfhi(v9) + bfhi(va) + bfhi(vb)
            + bfhi(vc) + bfhi(vd) + bfhi(ve) + bfhi(vf);
    }
    for (; i + 3 < e; i += 4) {
        int s0 = csr_src[i], s1 = csr_src[i + 1], s2 = csr_src[i + 2], s3 = csr_src[i + 3];
        unsigned int v0 = base[(size_t)s0 * 64 + lane];
        unsigned int v1 = base[(size_t)s1 * 64 + lane];
        unsigned int v2 = base[(size_t)s2 * 64 + lane];
        unsigned int v3 = base[(size_t)s3 * 64 + lane];
        ax += bflo(v0) + bflo(v1) + bflo(v2) + bflo(v3);
        ay += bfhi(v0) + bfhi(v1) + bfhi(v2) + bfhi(v3);
    }
    for (; i < e; ++i) {
        unsigned int v = base[(size_t)csr_src[i] * 64 + lane];
        ax += bflo(v); ay += bfhi(v);
    }
    ((unsigned int*)hb)[(size_t)node * 64 + lane] = packbf(ax, ay);
}

// ---------------- fused layer: out = relu(relu(BN(in@W1))@W2 + b2) ----------------
// 512 thr (8 waves), 128x128 tile, wave = 16 rows. B-fragments loaded directly
// global->VGPR (weights are 32 KB, device-wide shared -> L2/L3-hot; staging
// them per-block through LDS capped occupancy at 1 block/CU in R7).
// LDS = As (A tile, then H) + Cs (output staging) = 70 KB -> 2 blocks/CU.
// All H/C LDS traffic is wave-private (rows mbase..mbase+16) -> only 2 barriers.
__global__ __launch_bounds__(512) void fused_gemm(const ushort* __restrict__ in,
                                                  ushort* __restrict__ out,
                                                  const ushort* __restrict__ Wt1,
                                                  const ushort* __restrict__ Wt2,
                                                  const float* __restrict__ fold1,
                                                  const float* __restrict__ fold2) {
    __shared__ ushort As[128 * 136];    // A tile, then H tile (wave-private rows)
    __shared__ ushort Cs[128 * 136];    // output staging
    int t = threadIdx.x;
    int row0 = blockIdx.x * 128;        // 782 blocks, last partial (32 rows)

#pragma unroll
    for (int i = 0; i < 4; ++i) {
        int f = t + 512 * i; int m = f >> 4, g = f & 15;
        *(float4*)(As + m * 136 + g * 8) = *(const float4*)(in + (size_t)(row0 + m) * D + g * 8);
    }
    __syncthreads();

    int lane = t & 63, wv = t >> 6;
    int quad = lane >> 4, mr = lane & 15;
    int mbase = wv * 16;
    const ushort* ap = As + (mbase + mr) * 136 + quad * 8;
    bf16x8 a0 = *(const bf16x8*)(ap);
    bf16x8 a1 = *(const bf16x8*)(ap + 32);
    bf16x8 a2 = *(const bf16x8*)(ap + 64);
    bf16x8 a3 = *(const bf16x8*)(ap + 96);

    // --- GEMM1: H = relu(BN(A@W1)), H -> As (wave-private rows, no barrier)
#pragma unroll
    for (int nt = 0; nt < 8; ++nt) {
        const ushort* bq = Wt1 + (size_t)(nt * 16 + mr) * D + quad * 8;
        bf16x8 b0 = *(const bf16x8*)(bq);
        bf16x8 b1 = *(const bf16x8*)(bq + 32);
        bf16x8 b2 = *(const bf16x8*)(bq + 64);
        bf16x8 b3 = *(const bf16x8*)(bq + 96);
        f32x4 acc = {0.f, 0.f, 0.f, 0.f};
        acc = __builtin_amdgcn_mfma_f32_16x16x32_bf16(a0, b0, acc, 0, 0, 0);
        acc = __builtin_amdgcn_mfma_f32_16x16x32_bf16(a1, b1, acc, 0, 0, 0);
        acc = __builtin_amdgcn_mfma_f32_16x16x32_bf16(a2, b2, acc, 0, 0, 0);
        acc = __builtin_amdgcn_mfma_f32_16x16x32_bf16(a3, b3, acc, 0, 0, 0);
        int j = nt * 16 + mr;           // C/D: col=lane&15, row=quad*4+reg (m89)
        float s = fold1[j], o = fold1[D + j];
#pragma unroll
        for (int r = 0; r < 4; ++r) {
            float z = fmaxf(fmaf(acc[r], s, o), 0.0f);
            As[(mbase + quad * 4 + r) * 136 + j] = f2bf(z);
        }
    }

    // --- GEMM2: out = relu(H@W2 + b2); H read from own rows (in-wave ordered)
    const ushort* hp = As + (mbase + mr) * 136 + quad * 8;
    bf16x8 h0 = *(const bf16x8*)(hp);
    bf16x8 h1 = *(const bf16x8*)(hp + 32);
    bf16x8 h2 = *(const bf16x8*)(hp + 64);
    bf16x8 h3 = *(const bf16x8*)(hp + 96);
#pragma unroll
    for (int nt = 0; nt < 8; ++nt) {
        const ushort* bq = Wt2 + (size_t)(nt * 16 + mr) * D + quad * 8;
        bf16x8 b0 = *(const bf16x8*)(bq);
        bf16x8 b1 = *(const bf16x8*)(bq + 32);
        bf16x8 b2 = *(const bf16x8*)(bq + 64);
        bf16x8 b3 = *(const bf16x8*)(bq + 96);
        f32x4 acc = {0.f, 0.f, 0.f, 0.f};
        acc = __builtin_amdgcn_mfma_f32_16x16x32_bf16(h0, b0, acc, 0, 0, 0);
        acc = __builtin_amdgcn_mfma_f32_16x16x32_bf16(h1, b1, acc, 0, 0, 0);
        acc = __builtin_amdgcn_mfma_f32_16x16x32_bf16(h2, b2, acc, 0, 0, 0);
        acc = __builtin_amdgcn_mfma_f32_16x16x32_bf16(h3, b3, acc, 0, 0, 0);
        int j = nt * 16 + mr;
        float o = fold2[D + j];
#pragma unroll
        for (int r = 0; r < 4; ++r) {
            float z = fmaxf(acc[r] + o, 0.0f);
            Cs[(mbase + quad * 4 + r) * 136 + j] = f2bf(z);
        }
    }
    __syncthreads();

#pragma unroll
    for (int i = 0; i < 8; ++i) {       // coalesced copy-out, float2 = 4 bf16
        int f = t + 512 * i; int lr = f >> 5, g = f & 31;
        if (row0 + lr < N_NODES)
            *(float2*)(out + (size_t)(row0 + lr) * D + g * 4) =
                *(const float2*)(Cs + lr * 136 + g * 4);
    }
}

// ---------------- pooling (bf16 in, fp32 out) ----------------
__global__ __launch_bounds__(128) void pool_kernel(const ushort* __restrict__ xb,
                                                   const int* __restrict__ gstart,
                                                   float* __restrict__ g) {
    int gr = blockIdx.x, j = threadIdx.x;
    float acc = 0.0f;
    int b = gstart[gr], e = gstart[gr + 1];
    for (int i = b; i < e; ++i)
        acc += __uint_as_float(((unsigned int)xb[(size_t)i * D + j]) << 16);
    g[gr * D + j] = acc;
}

// ---------------- head (fp32) ----------------
__global__ __launch_bounds__(128) void head_kernel(const float* __restrict__ g,
                                                   const float* __restrict__ W1,
                                                   const float* __restrict__ b1,
                                                   const float* __restrict__ W2,
                                                   const float* __restrict__ b2,
                                                   float* __restrict__ out) {
    __shared__ float row[128];
    __shared__ float t1[128];
    int r = blockIdx.x, j = threadIdx.x;
    row[j] = g[r * D + j];
    __syncthreads();
    float acc = b1[j];
    for (int k = 0; k < D; ++k) acc = fmaf(row[k], W1[k * D + j], acc);
    t1[j] = fmaxf(acc, 0.0f);
    __syncthreads();
    float acc2 = b2[j];
    for (int k = 0; k < D; ++k) acc2 = fmaf(t1[k], W2[k * D + j], acc2);
    out[r * D + j] = acc2;
}

// ---------------- launcher ----------------
extern "C" void kernel_launch(void* const* d_in, const int* in_sizes, int n_in,
                              void* d_out, int out_size, void* d_ws, size_t ws_size,
                              hipStream_t stream) {
    const float* x        = (const float*)d_in[0];
    const int*   ei       = (const int*)d_in[1];
    const int*   src      = ei;
    const int*   dst      = ei + N_EDGES;
    const int*   batch    = (const int*)d_in[2];
    const float* conv_W1  = (const float*)d_in[3];
    const float* conv_b1  = (const float*)d_in[4];
    const float* bn_gamma = (const float*)d_in[5];
    const float* bn_beta  = (const float*)d_in[6];
    const float* bn_mean  = (const float*)d_in[7];
    const float* bn_var   = (const float*)d_in[8];
    const float* conv_W2  = (const float*)d_in[9];
    const float* conv_b2  = (const float*)d_in[10];
    const float* head_W1  = (const float*)d_in[11];
    const float* head_b1  = (const float*)d_in[12];
    const float* head_W2  = (const float*)d_in[13];
    const float* head_b2  = (const float*)d_in[14];
    float* out = (float*)d_out;

    char* ws = (char*)d_ws;
    size_t off = 0;
    auto alloc = [&](size_t bytes) -> void* {
        void* p = ws + off;
        off = (off + bytes + 255) & ~(size_t)255;
        return p;
    };
    const size_t NODE_BUF = (size_t)(N_NODES + 128) * D * sizeof(ushort);
    ushort* buf0    = (ushort*)alloc(NODE_BUF);
    ushort* buf1    = (ushort*)alloc(NODE_BUF);
    ushort* Wt      = (ushort*)alloc((size_t)6 * D * D * sizeof(ushort));
    float*  folds   = (float*)alloc((size_t)6 * 2 * D * sizeof(float));
    unsigned int* squeue = (unsigned int*)alloc((size_t)FNSLICE * FSLICE_CAP * sizeof(unsigned int));
    int*   csr_src  = (int*)alloc((size_t)N_EDGES * sizeof(int));
    int*   offsets  = (int*)alloc((size_t)(N_NODES + 1) * sizeof(int));
    int*   slice_tail = (int*)alloc((size_t)FNSLICE * sizeof(int));
    int*   slice_base = (int*)alloc((size_t)FNSLICE * sizeof(int));
    int*   gstart   = (int*)alloc((size_t)(N_GRAPHS + 1) * sizeof(int));
    float* gpool    = (float*)alloc((size_t)N_GRAPHS * D * sizeof(float));

    zero_kernel<<<1, 128, 0, stream>>>(slice_tail, FNSLICE);
    compact_kernel<<<CGRID, 256, 0, stream>>>(src, dst, squeue, slice_tail);
    slice_scan<<<1, 128, 0, stream>>>(slice_tail, slice_base, offsets);
    fill_local<<<FNSLICE, 1024, 0, stream>>>(squeue, slice_tail, slice_base,
                                             offsets, csr_src);
    gstart_kernel<<<(N_GRAPHS + 1 + 255) / 256, 256, 0, stream>>>(batch, gstart);
    cvt_x_kernel<<<(N_NODES * D) / (256 * 8), 256, 0, stream>>>(x, buf0);
    prep_w_kernel<<<dim3(128, 6), 128, 0, stream>>>(conv_W1, conv_W2, Wt);
    prep_fold_kernel<<<6, 128, 0, stream>>>(conv_b1, bn_gamma, bn_beta,
                                            bn_mean, bn_var, conv_b2, folds);

    const int FUSED_GRID = (N_NODES + 127) / 128;   // 782
    for (int l = 0; l < 3; ++l) {
        gather_bf16<<<N_NODES / 4, 256, 0, stream>>>(buf0, offsets, csr_src, buf1);
        fused_gemm<<<FUSED_GRID, 512, 0, stream>>>(buf1, buf0,
            Wt + (size_t)(2 * l) * D * D, Wt + (size_t)(2 * l + 1) * D * D,
            folds + (size_t)(2 * l) * 2 * D, folds + (size_t)(2 * l + 1) * 2 * D);
    }

    pool_kernel<<<N_GRAPHS, 128, 0, stream>>>(buf0, gstart, gpool);
    head_kernel<<<N_GRAPHS, 128, 0, stream>>>(gpool, head_W1, head_b1,
                                              head_W2, head_b2, out);
}

// Round 9
// 457.481 us; speedup vs baseline: 1.2889x; 1.2889x over previous
//
#include <hip/hip_runtime.h>

#define N_NODES  100000
#define N_EDGES  1600000
#define N_GRAPHS 1024
#define D        128
#define BN_EPS   1e-5f

// --- atomic-free CSR build geometry ---
#define FNSLICE      98                  // ceil(100000/1024) node slices
#define FSLICE_NODES 1024                // nodes per slice (d>>10)
#define FSLICE_CAP   20480               // queue cap: mean 16384, sigma~127
#define QCAP         96                  // per-block LDS bin: mean 41, +12 sigma
#define CCHUNK       4000
#define CGRID        400                 // 400*4000 == N_EDGES

typedef short bf16x8 __attribute__((ext_vector_type(8)));
typedef float f32x4  __attribute__((ext_vector_type(4)));

__device__ __forceinline__ ushort f2bf(float f) {        // RNE fp32->bf16
    unsigned int b = __float_as_uint(f);
    return (ushort)((b + 0x7fffu + ((b >> 16) & 1u)) >> 16);
}
__device__ __forceinline__ float bflo(unsigned int u) { return __uint_as_float(u << 16); }
__device__ __forceinline__ float bfhi(unsigned int u) { return __uint_as_float(u & 0xffff0000u); }
__device__ __forceinline__ unsigned int packbf(float x, float y) {
    return (unsigned int)f2bf(x) | ((unsigned int)f2bf(y) << 16);
}

// ---------------- CSR build (no global atomics on hot paths) ----------------

__global__ void zero_kernel(int* __restrict__ p, int n) {
    int i = blockIdx.x * blockDim.x + threadIdx.x;
    if (i < n) p[i] = 0;
}

__global__ __launch_bounds__(256) void compact_kernel(const int* __restrict__ src,
                                                      const int* __restrict__ dst,
                                                      unsigned int* __restrict__ squeue,
                                                      int* __restrict__ slice_tail) {
    __shared__ unsigned int qbuf[FNSLICE * QCAP];   // 37.6 KB
    __shared__ int qcnt[FNSLICE];
    __shared__ int qbase[FNSLICE];
    int t = threadIdx.x;
    for (int i = t; i < FNSLICE; i += 256) qcnt[i] = 0;
    __syncthreads();
    int e0 = blockIdx.x * CCHUNK;
    int eend = e0 + CCHUNK; if (eend > N_EDGES) eend = N_EDGES;
    for (int e = e0 + t; e < eend; e += 256) {
        int d = dst[e], s = src[e];
        int sl = d >> 10;
        unsigned int pk = ((unsigned int)(d & 1023) << 17) | (unsigned int)s;
        int pos = atomicAdd(&qcnt[sl], 1);
        if (pos < QCAP) qbuf[sl * QCAP + pos] = pk;
        else {  // ~never (12-sigma): direct spill, still correct
            int gp = atomicAdd(&slice_tail[sl], 1);
            squeue[(size_t)sl * FSLICE_CAP + gp] = pk;
        }
    }
    __syncthreads();
    for (int i = t; i < FNSLICE; i += 256) {
        int n = qcnt[i]; if (n > QCAP) n = QCAP;
        qbase[i] = atomicAdd(&slice_tail[i], n);
    }
    __syncthreads();
    int wv = t >> 6, ln = t & 63;
    for (int sl = wv; sl < FNSLICE; sl += 4) {
        int n = qcnt[sl]; if (n > QCAP) n = QCAP;
        int gb = qbase[sl];
        for (int i = ln; i < n; i += 64)
            squeue[(size_t)sl * FSLICE_CAP + gb + i] = qbuf[sl * QCAP + i];
    }
}

__global__ __launch_bounds__(128) void slice_scan(const int* __restrict__ slice_tail,
                                                  int* __restrict__ slice_base,
                                                  int* __restrict__ offsets) {
    __shared__ int part[128];
    int t = threadIdx.x;
    int v = (t < FNSLICE) ? slice_tail[t] : 0;
    part[t] = v;
    __syncthreads();
    for (int off = 1; off < 128; off <<= 1) {
        int u = (t >= off) ? part[t - off] : 0;
        __syncthreads();
        part[t] += u;
        __syncthreads();
    }
    if (t < FNSLICE) slice_base[t] = part[t] - v;
    if (t == 0) offsets[N_NODES] = N_EDGES;
}

__global__ __launch_bounds__(1024) void fill_local(const unsigned int* __restrict__ squeue,
                                                   const int* __restrict__ slice_tail,
                                                   const int* __restrict__ slice_base,
                                                   int* __restrict__ offsets,
                                                   int* __restrict__ csr_src) {
    __shared__ int hist[FSLICE_NODES];
    __shared__ int cur[FSLICE_NODES];
    int sl = blockIdx.x, t = threadIdx.x;
    int n = slice_tail[sl];
    size_t qb = (size_t)sl * FSLICE_CAP;
    int gbase = slice_base[sl];
    hist[t] = 0;
    __syncthreads();
    for (int i = t; i < n; i += 1024)
        atomicAdd(&hist[squeue[qb + i] >> 17], 1);
    __syncthreads();
    int v = hist[t];
    for (int off = 1; off < 1024; off <<= 1) {       // inclusive Hillis-Steele
        int u = (t >= off) ? hist[t - off] : 0;
        __syncthreads();
        hist[t] += u;
        __syncthreads();
    }
    int excl = hist[t] - v;
    cur[t] = excl;
    int node = sl * FSLICE_NODES + t;
    if (node < N_NODES) offsets[node] = gbase + excl;
    __syncthreads();
    for (int i = t; i < n; i += 1024) {
        unsigned int p = squeue[qb + i];
        int slot = atomicAdd(&cur[p >> 17], 1);      // LDS atomic
        csr_src[gbase + slot] = (int)(p & 0x1FFFFu);
    }
}

__global__ void gstart_kernel(const int* __restrict__ batch, int* __restrict__ gstart) {
    int g = blockIdx.x * blockDim.x + threadIdx.x;
    if (g > N_GRAPHS) return;
    int lo = 0, hi = N_NODES;
    while (lo < hi) {
        int mid = (lo + hi) >> 1;
        if (batch[mid] < g) lo = mid + 1; else hi = mid;
    }
    gstart[g] = lo;
}

// ---------------- precompute ----------------

__global__ __launch_bounds__(256) void cvt_x_kernel(const float* __restrict__ x,
                                                    ushort* __restrict__ xb) {
    size_t i = ((size_t)blockIdx.x * 256 + threadIdx.x) * 8;   // 6250 blocks exact
    float4 v0 = *(const float4*)(x + i);
    float4 v1 = *(const float4*)(x + i + 4);
    uint4 o;
    o.x = packbf(v0.x, v0.y); o.y = packbf(v0.z, v0.w);
    o.z = packbf(v1.x, v1.y); o.w = packbf(v1.z, v1.w);
    *(uint4*)(xb + i) = o;
}

__global__ __launch_bounds__(128) void prep_w_kernel(const float* __restrict__ W1,
                                                     const float* __restrict__ W2,
                                                     ushort* __restrict__ Wt) {
    int i = blockIdx.y, k = blockIdx.x, n = threadIdx.x, l = i >> 1;
    const float* W = (i & 1) ? (W2 + (size_t)l * D * D) : (W1 + (size_t)l * D * D);
    Wt[(size_t)i * D * D + n * D + k] = f2bf(W[k * D + n]);
}

__global__ __launch_bounds__(128) void prep_fold_kernel(
        const float* __restrict__ b1, const float* __restrict__ gamma,
        const float* __restrict__ beta, const float* __restrict__ mean,
        const float* __restrict__ var, const float* __restrict__ b2,
        float* __restrict__ folds) {
    int i = blockIdx.x, j = threadIdx.x, l = i >> 1;
    float s, o;
    if ((i & 1) == 0) {
        float sv = gamma[l * D + j] * rsqrtf(var[l * D + j] + BN_EPS);
        s = sv;
        o = (b1[l * D + j] - mean[l * D + j]) * sv + beta[l * D + j];
    } else {
        s = 1.0f;
        o = b2[l * D + j];
    }
    folds[(size_t)i * 2 * D + j]     = s;
    folds[(size_t)i * 2 * D + D + j] = o;
}

// ---------------- aggregation (bf16 rows, fp32 accumulate, 16 outstanding) ----------------
__global__ __launch_bounds__(256) void gather_bf16(const ushort* __restrict__ xb,
                                                   const int* __restrict__ offsets,
                                                   const int* __restrict__ csr_src,
                                                   ushort* __restrict__ hb) {
    int wv = threadIdx.x >> 6, lane = threadIdx.x & 63;
    int node = blockIdx.x * 4 + wv;           // 25000*4 == N_NODES
    const unsigned int* base = (const unsigned int*)xb;
    unsigned int u = base[(size_t)node * 64 + lane];
    float ax = bflo(u), ay = bfhi(u);
    int b = offsets[node], e = offsets[node + 1];
    int i = b;
    for (; i + 15 < e; i += 16) {             // 16 outstanding row loads
        int s0 = csr_src[i],      s1 = csr_src[i + 1],  s2 = csr_src[i + 2],  s3 = csr_src[i + 3];
        int s4 = csr_src[i + 4],  s5 = csr_src[i + 5],  s6 = csr_src[i + 6],  s7 = csr_src[i + 7];
        int s8 = csr_src[i + 8],  s9 = csr_src[i + 9],  sa = csr_src[i + 10], sb = csr_src[i + 11];
        int sc = csr_src[i + 12], sd = csr_src[i + 13], se = csr_src[i + 14], sf = csr_src[i + 15];
        unsigned int v0 = base[(size_t)s0 * 64 + lane];
        unsigned int v1 = base[(size_t)s1 * 64 + lane];
        unsigned int v2 = base[(size_t)s2 * 64 + lane];
        unsigned int v3 = base[(size_t)s3 * 64 + lane];
        unsigned int v4 = base[(size_t)s4 * 64 + lane];
        unsigned int v5 = base[(size_t)s5 * 64 + lane];
        unsigned int v6 = base[(size_t)s6 * 64 + lane];
        unsigned int v7 = base[(size_t)s7 * 64 + lane];
        unsigned int v8 = base[(size_t)s8 * 64 + lane];
        unsigned int v9 = base[(size_t)s9 * 64 + lane];
        unsigned int va = base[(size_t)sa * 64 + lane];
        unsigned int vb = base[(size_t)sb * 64 + lane];
        unsigned int vc = base[(size_t)sc * 64 + lane];
        unsigned int vd = base[(size_t)sd * 64 + lane];
        unsigned int ve = base[(size_t)se * 64 + lane];
        unsigned int vf = base[(size_t)sf * 64 + lane];
        ax += bflo(v0) + bflo(v1) + bflo(v2) + bflo(v3)
            + bflo(v4) + bflo(v5) + bflo(v6) + bflo(v7)
            + bflo(v8) + bflo(v9) + bflo(va) + bflo(vb)
            + bflo(vc) + bflo(vd) + bflo(ve) + bflo(vf);
        ay += bfhi(v0) + bfhi(v1) + bfhi(v2) + bfhi(v3)
            + bfhi(v4) + bfhi(v5) + bfhi(v6) + bfhi(v7)
            + bfhi(v8) + bfhi(v9) + bfhi(va) + bfhi(vb)
            + bfhi(vc) + bfhi(vd) + bfhi(ve) + bfhi(vf);
    }
    for (; i + 3 < e; i += 4) {
        int s0 = csr_src[i], s1 = csr_src[i + 1], s2 = csr_src[i + 2], s3 = csr_src[i + 3];
        unsigned int v0 = base[(size_t)s0 * 64 + lane];
        unsigned int v1 = base[(size_t)s1 * 64 + lane];
        unsigned int v2 = base[(size_t)s2 * 64 + lane];
        unsigned int v3 = base[(size_t)s3 * 64 + lane];
        ax += bflo(v0) + bflo(v1) + bflo(v2) + bflo(v3);
        ay += bfhi(v0) + bfhi(v1) + bfhi(v2) + bfhi(v3);
    }
    for (; i < e; ++i) {
        unsigned int v = base[(size_t)csr_src[i] * 64 + lane];
        ax += bflo(v); ay += bfhi(v);
    }
    ((unsigned int*)hb)[(size_t)node * 64 + lane] = packbf(ax, ay);
}

// ---------------- fused layer: out = relu(relu(BN(in@W1))@W2 + b2) ----------------
// 512 thr (8 waves), 128x128 tile, wave = 16 rows.
// LDS = As (A -> H -> C, all wave-private row reuse) + ONE Bs buffer staged
// with W1 then re-staged with W2 after the gemm1 barrier. 68 KB -> 2 blocks/CU
// (R8 lesson: direct global->VGPR B loads serialize on vmcnt at low occupancy;
// R7 lesson: 3 LDS buffers = 104 KB caps occupancy at 1 block/CU).
__global__ __launch_bounds__(512, 4) void fused_gemm(const ushort* __restrict__ in,
                                                     ushort* __restrict__ out,
                                                     const ushort* __restrict__ Wt1,
                                                     const ushort* __restrict__ Wt2,
                                                     const float* __restrict__ fold1,
                                                     const float* __restrict__ fold2) {
    __shared__ ushort As[128 * 136];    // A tile -> H tile -> C tile (aliased)
    __shared__ ushort Bs[128 * 136];    // W1^T, then W2^T
    int t = threadIdx.x;
    int row0 = blockIdx.x * 128;        // 782 blocks, last partial (32 rows)

#pragma unroll
    for (int i = 0; i < 4; ++i) {       // stage A + W1
        int f = t + 512 * i; int m = f >> 4, g = f & 15;
        *(float4*)(As + m * 136 + g * 8) = *(const float4*)(in + (size_t)(row0 + m) * D + g * 8);
        *(float4*)(Bs + m * 136 + g * 8) = *(const float4*)(Wt1 + (size_t)m * D + g * 8);
    }
    __syncthreads();

    int lane = t & 63, wv = t >> 6;
    int quad = lane >> 4, mr = lane & 15;
    int mbase = wv * 16;
    const ushort* ap = As + (mbase + mr) * 136 + quad * 8;
    bf16x8 a0 = *(const bf16x8*)(ap);
    bf16x8 a1 = *(const bf16x8*)(ap + 32);
    bf16x8 a2 = *(const bf16x8*)(ap + 64);
    bf16x8 a3 = *(const bf16x8*)(ap + 96);

    // --- GEMM1: H = relu(BN(A@W1)) -> As own rows (in-wave DS ordering: safe)
#pragma unroll
    for (int nt = 0; nt < 8; ++nt) {
        const ushort* bq = Bs + (nt * 16 + mr) * 136 + quad * 8;
        bf16x8 b0 = *(const bf16x8*)(bq);
        bf16x8 b1 = *(const bf16x8*)(bq + 32);
        bf16x8 b2 = *(const bf16x8*)(bq + 64);
        bf16x8 b3 = *(const bf16x8*)(bq + 96);
        f32x4 acc = {0.f, 0.f, 0.f, 0.f};
        acc = __builtin_amdgcn_mfma_f32_16x16x32_bf16(a0, b0, acc, 0, 0, 0);
        acc = __builtin_amdgcn_mfma_f32_16x16x32_bf16(a1, b1, acc, 0, 0, 0);
        acc = __builtin_amdgcn_mfma_f32_16x16x32_bf16(a2, b2, acc, 0, 0, 0);
        acc = __builtin_amdgcn_mfma_f32_16x16x32_bf16(a3, b3, acc, 0, 0, 0);
        int j = nt * 16 + mr;           // C/D: col=lane&15, row=quad*4+reg (m89)
        float s = fold1[j], o = fold1[D + j];
#pragma unroll
        for (int r = 0; r < 4; ++r) {
            float z = fmaxf(fmaf(acc[r], s, o), 0.0f);
            As[(mbase + quad * 4 + r) * 136 + j] = f2bf(z);
        }
    }
    __syncthreads();                    // all waves done reading W1 from Bs

#pragma unroll
    for (int i = 0; i < 4; ++i) {       // re-stage Bs with W2
        int f = t + 512 * i; int m = f >> 4, g = f & 15;
        *(float4*)(Bs + m * 136 + g * 8) = *(const float4*)(Wt2 + (size_t)m * D + g * 8);
    }
    // h-frag loads from own rows overlap the staging stores (no barrier needed
    // for As: H rows are wave-private)
    const ushort* hp = As + (mbase + mr) * 136 + quad * 8;
    bf16x8 h0 = *(const bf16x8*)(hp);
    bf16x8 h1 = *(const bf16x8*)(hp + 32);
    bf16x8 h2 = *(const bf16x8*)(hp + 64);
    bf16x8 h3 = *(const bf16x8*)(hp + 96);
    __syncthreads();                    // W2 staged

    // --- GEMM2: C = relu(H@W2 + b2) -> As own rows (aliases H, loaded above)
#pragma unroll
    for (int nt = 0; nt < 8; ++nt) {
        const ushort* bq = Bs + (nt * 16 + mr) * 136 + quad * 8;
        bf16x8 b0 = *(const bf16x8*)(bq);
        bf16x8 b1 = *(const bf16x8*)(bq + 32);
        bf16x8 b2 = *(const bf16x8*)(bq + 64);
        bf16x8 b3 = *(const bf16x8*)(bq + 96);
        f32x4 acc = {0.f, 0.f, 0.f, 0.f};
        acc = __builtin_amdgcn_mfma_f32_16x16x32_bf16(h0, b0, acc, 0, 0, 0);
        acc = __builtin_amdgcn_mfma_f32_16x16x32_bf16(h1, b1, acc, 0, 0, 0);
        acc = __builtin_amdgcn_mfma_f32_16x16x32_bf16(h2, b2, acc, 0, 0, 0);
        acc = __builtin_amdgcn_mfma_f32_16x16x32_bf16(h3, b3, acc, 0, 0, 0);
        int j = nt * 16 + mr;
        float o = fold2[D + j];
#pragma unroll
        for (int r = 0; r < 4; ++r) {
            float z = fmaxf(acc[r] + o, 0.0f);
            As[(mbase + quad * 4 + r) * 136 + j] = f2bf(z);
        }
    }
    __syncthreads();

#pragma unroll
    for (int i = 0; i < 8; ++i) {       // coalesced copy-out, float2 = 4 bf16
        int f = t + 512 * i; int lr = f >> 5, g = f & 31;
        if (row0 + lr < N_NODES)
            *(float2*)(out + (size_t)(row0 + lr) * D + g * 4) =
                *(const float2*)(As + lr * 136 + g * 4);
    }
}

// ---------------- pooling (bf16 in, fp32 out) ----------------
__global__ __launch_bounds__(128) void pool_kernel(const ushort* __restrict__ xb,
                                                   const int* __restrict__ gstart,
                                                   float* __restrict__ g) {
    int gr = blockIdx.x, j = threadIdx.x;
    float acc = 0.0f;
    int b = gstart[gr], e = gstart[gr + 1];
    for (int i = b; i < e; ++i)
        acc += __uint_as_float(((unsigned int)xb[(size_t)i * D + j]) << 16);
    g[gr * D + j] = acc;
}

// ---------------- head (fp32) ----------------
__global__ __launch_bounds__(128) void head_kernel(const float* __restrict__ g,
                                                   const float* __restrict__ W1,
                                                   const float* __restrict__ b1,
                                                   const float* __restrict__ W2,
                                                   const float* __restrict__ b2,
                                                   float* __restrict__ out) {
    __shared__ float row[128];
    __shared__ float t1[128];
    int r = blockIdx.x, j = threadIdx.x;
    row[j] = g[r * D + j];
    __syncthreads();
    float acc = b1[j];
    for (int k = 0; k < D; ++k) acc = fmaf(row[k], W1[k * D + j], acc);
    t1[j] = fmaxf(acc, 0.0f);
    __syncthreads();
    float acc2 = b2[j];
    for (int k = 0; k < D; ++k) acc2 = fmaf(t1[k], W2[k * D + j], acc2);
    out[r * D + j] = acc2;
}

// ---------------- launcher ----------------
extern "C" void kernel_launch(void* const* d_in, const int* in_sizes, int n_in,
                              void* d_out, int out_size, void* d_ws, size_t ws_size,
                              hipStream_t stream) {
    const float* x        = (const float*)d_in[0];
    const int*   ei       = (const int*)d_in[1];
    const int*   src      = ei;
    const int*   dst      = ei + N_EDGES;
    const int*   batch    = (const int*)d_in[2];
    const float* conv_W1  = (const float*)d_in[3];
    const float* conv_b1  = (const float*)d_in[4];
    const float* bn_gamma = (const float*)d_in[5];
    const float* bn_beta  = (const float*)d_in[6];
    const float* bn_mean  = (const float*)d_in[7];
    const float* bn_var   = (const float*)d_in[8];
    const float* conv_W2  = (const float*)d_in[9];
    const float* conv_b2  = (const float*)d_in[10];
    const float* head_W1  = (const float*)d_in[11];
    const float* head_b1  = (const float*)d_in[12];
    const float* head_W2  = (const float*)d_in[13];
    const float* head_b2  = (const float*)d_in[14];
    float* out = (float*)d_out;

    char* ws = (char*)d_ws;
    size_t off = 0;
    auto alloc = [&](size_t bytes) -> void* {
        void* p = ws + off;
        off = (off + bytes + 255) & ~(size_t)255;
        return p;
    };
    const size_t NODE_BUF = (size_t)(N_NODES + 128) * D * sizeof(ushort);
    ushort* buf0    = (ushort*)alloc(NODE_BUF);
    ushort* buf1    = (ushort*)alloc(NODE_BUF);
    ushort* Wt      = (ushort*)alloc((size_t)6 * D * D * sizeof(ushort));
    float*  folds   = (float*)alloc((size_t)6 * 2 * D * sizeof(float));
    unsigned int* squeue = (unsigned int*)alloc((size_t)FNSLICE * FSLICE_CAP * sizeof(unsigned int));
    int*   csr_src  = (int*)alloc((size_t)N_EDGES * sizeof(int));
    int*   offsets  = (int*)alloc((size_t)(N_NODES + 1) * sizeof(int));
    int*   slice_tail = (int*)alloc((size_t)FNSLICE * sizeof(int));
    int*   slice_base = (int*)alloc((size_t)FNSLICE * sizeof(int));
    int*   gstart   = (int*)alloc((size_t)(N_GRAPHS + 1) * sizeof(int));
    float* gpool    = (float*)alloc((size_t)N_GRAPHS * D * sizeof(float));

    zero_kernel<<<1, 128, 0, stream>>>(slice_tail, FNSLICE);
    compact_kernel<<<CGRID, 256, 0, stream>>>(src, dst, squeue, slice_tail);
    slice_scan<<<1, 128, 0, stream>>>(slice_tail, slice_base, offsets);
    fill_local<<<FNSLICE, 1024, 0, stream>>>(squeue, slice_tail, slice_base,
                                             offsets, csr_src);
    gstart_kernel<<<(N_GRAPHS + 1 + 255) / 256, 256, 0, stream>>>(batch, gstart);
    cvt_x_kernel<<<(N_NODES * D) / (256 * 8), 256, 0, stream>>>(x, buf0);
    prep_w_kernel<<<dim3(128, 6), 128, 0, stream>>>(conv_W1, conv_W2, Wt);
    prep_fold_kernel<<<6, 128, 0, stream>>>(conv_b1, bn_gamma, bn_beta,
                                            bn_mean, bn_var, conv_b2, folds);

    const int FUSED_GRID = (N_NODES + 127) / 128;   // 782
    for (int l = 0; l < 3; ++l) {
        gather_bf16<<<N_NODES / 4, 256, 0, stream>>>(buf0, offsets, csr_src, buf1);
        fused_gemm<<<FUSED_GRID, 512, 0, stream>>>(buf1, buf0,
            Wt + (size_t)(2 * l) * D * D, Wt + (size_t)(2 * l + 1) * D * D,
            folds + (size_t)(2 * l) * 2 * D, folds + (size_t)(2 * l + 1) * 2 * D);
    }

    pool_kernel<<<N_GRAPHS, 128, 0, stream>>>(buf0, gstart, gpool);
    head_kernel<<<N_GRAPHS, 128, 0, stream>>>(gpool, head_W1, head_b1,
                                              head_W2, head_b2, out);
}